// Round 2
// baseline (1565.158 us; speedup 1.0000x reference)
//
#include <hip/hip_runtime.h>
#include <stdint.h>

#define M_DIM 8192
#define K_DIM 4096
#define N_DIM 11008
#define NPACK 1376   // N/8

typedef __attribute__((ext_vector_type(8))) short short8;
typedef __attribute__((ext_vector_type(4))) float f32x4;
typedef __attribute__((ext_vector_type(4))) float float4v;

typedef const void __attribute__((address_space(1)))* as1_cvp;
typedef void __attribute__((address_space(3)))* as3_vp;

__device__ __forceinline__ void glds16(const void* g, void* l) {
  __builtin_amdgcn_global_load_lds((as1_cvp)g, (as3_vp)l, 16, 0, 0);
}

__device__ __forceinline__ unsigned short f2bf(float f) {
  uint32_t u = __float_as_uint(f);
  u += 0x7FFFu + ((u >> 16) & 1u);   // RNE; inputs are finite/normal
  return (unsigned short)(u >> 16);
}

// ---------------- x fp32 -> bf16 ----------------
__global__ void cvt_x_kernel(const float* __restrict__ x, short* __restrict__ o) {
  int i = blockIdx.x * blockDim.x + threadIdx.x;   // exactly M*K/8 threads
  const float4v* xv = (const float4v*)x;
  float4v a = xv[2 * i];
  float4v b = xv[2 * i + 1];
  short8 r;
  r[0] = (short)f2bf(a[0]); r[1] = (short)f2bf(a[1]);
  r[2] = (short)f2bf(a[2]); r[3] = (short)f2bf(a[3]);
  r[4] = (short)f2bf(b[0]); r[5] = (short)f2bf(b[1]);
  r[6] = (short)f2bf(b[2]); r[7] = (short)f2bf(b[3]);
  ((short8*)o)[i] = r;
}

// ---------------- AWQ dequant -> W^T [N][K] bf16 ----------------
// Tile: 64 k  x 256 n (32 packed ints). 256 threads: lane->k (coalesced 2B
// stores along k), tid>>6 -> packed-col quarter. Reads hit L1/L2 lines shared
// across the pp loop.
__global__ void dequant_kernel(const int* __restrict__ qw, const int* __restrict__ qz,
                               const float* __restrict__ sc, short* __restrict__ Wt,
                               int n_chunk_base) {
  const int k0 = blockIdx.x * 64;
  const int ntile = n_chunk_base + blockIdx.y * 256;  // global n start of tile
  const int kl = threadIdx.x & 63;
  const int pc = threadIdx.x >> 6;                    // 0..3
  const int g = k0 >> 7;                              // group (k0 mult of 64 => exact)
  const int k = k0 + kl;
  constexpr int SH[8] = {0, 16, 4, 20, 8, 24, 12, 28}; // 4*rev[j], rev=[0,4,1,5,2,6,3,7]
#pragma unroll
  for (int pp = 0; pp < 8; ++pp) {
    const int p = (ntile >> 3) + pc * 8 + pp;         // global packed col
    const uint32_t q = (uint32_t)qw[(size_t)k * NPACK + p];
    const uint32_t z = (uint32_t)qz[(size_t)g * NPACK + p];
    const float4v s0 = *(const float4v*)&sc[(size_t)g * N_DIM + p * 8];
    const float4v s1 = *(const float4v*)&sc[(size_t)g * N_DIM + p * 8 + 4];
    const int nloc = p * 8 - n_chunk_base;            // chunk-local n of j=0
#pragma unroll
    for (int j = 0; j < 8; ++j) {
      const int wv = (int)((q >> SH[j]) & 0xFu) - (int)((z >> SH[j]) & 0xFu);
      const float scl = (j < 4) ? s0[j] : s1[j - 4];
      Wt[(size_t)(nloc + j) * K_DIM + k] = (short)f2bf((float)wv * scl);
    }
  }
}

// ---------------- bf16 GEMM: C = A * Wt^T + bias ----------------
// m97 structure: 128x128 tile, BK=32, 4 waves x (64x64 = 4x4 frags of 16x16x32),
// global_load_lds width-16 staging, 2 barriers per K-step.
__global__ __launch_bounds__(256) void gemm_kernel(
    const short* __restrict__ A,    // [M][K] bf16
    const short* __restrict__ Bt,   // [nc][K] bf16, chunk-local rows
    const float* __restrict__ bias,
    float* __restrict__ C,
    int n_base) {
  __shared__ short As[128 * 32];
  __shared__ short Bs[128 * 32];

  const int tid = threadIdx.x;
  const int wave = tid >> 6;
  const int lane = tid & 63;
  const int m0 = blockIdx.y * 128;
  const int nloc0 = blockIdx.x * 128;     // row base into Bt
  const int ng0 = n_base + nloc0;         // global col base

  // staging: 8 chunks of 1024B per tile; wave w owns chunks 2w, 2w+1.
  const int c0 = wave * 2;
  const int srow = lane >> 2;             // 0..15
  const int scol = (lane & 3) * 8;        // 0,8,16,24
  const short* gA0 = A + (size_t)(m0 + c0 * 16 + srow) * K_DIM + scol;
  const short* gA1 = gA0 + (size_t)16 * K_DIM;
  const short* gB0 = Bt + (size_t)(nloc0 + c0 * 16 + srow) * K_DIM + scol;
  const short* gB1 = gB0 + (size_t)16 * K_DIM;
  short* lA0 = &As[c0 * 512];             // wave-uniform LDS bases
  short* lA1 = &As[(c0 + 1) * 512];
  short* lB0 = &Bs[c0 * 512];
  short* lB1 = &Bs[(c0 + 1) * 512];

  const int wr = wave >> 1, wc = wave & 1;
  const int fr = lane & 15;
  const int kb = (lane >> 4) * 8;
  const short* fA = &As[(wr * 64 + fr) * 32 + kb];
  const short* fB = &Bs[(wc * 64 + fr) * 32 + kb];

  f32x4 acc[4][4] = {};

  for (int kt = 0; kt < K_DIM; kt += 32) {
    glds16(gA0 + kt, lA0);
    glds16(gA1 + kt, lA1);
    glds16(gB0 + kt, lB0);
    glds16(gB1 + kt, lB1);
    __syncthreads();                      // vmcnt(0) drain + barrier
    short8 a[4], b[4];
#pragma unroll
    for (int m = 0; m < 4; ++m) a[m] = *(const short8*)(fA + m * 16 * 32);
#pragma unroll
    for (int n = 0; n < 4; ++n) b[n] = *(const short8*)(fB + n * 16 * 32);
#pragma unroll
    for (int m = 0; m < 4; ++m)
#pragma unroll
      for (int n = 0; n < 4; ++n)
        acc[m][n] = __builtin_amdgcn_mfma_f32_16x16x32_bf16(a[m], b[n], acc[m][n], 0, 0, 0);
    __syncthreads();                      // reads done before next stage
  }

  // epilogue: C/D map col=lane&15, row=(lane>>4)*4+r (m89-verified)
  const int cr = (lane >> 4) * 4;
  const int cc = lane & 15;
#pragma unroll
  for (int n = 0; n < 4; ++n) {
    const int col = ng0 + wc * 64 + n * 16 + cc;
    const float bv = bias[col];
#pragma unroll
    for (int m = 0; m < 4; ++m) {
      const int row = m0 + wr * 64 + m * 16 + cr;
      const f32x4 v = acc[m][n];
      C[(size_t)(row + 0) * N_DIM + col] = v[0] + bv;
      C[(size_t)(row + 1) * N_DIM + col] = v[1] + bv;
      C[(size_t)(row + 2) * N_DIM + col] = v[2] + bv;
      C[(size_t)(row + 3) * N_DIM + col] = v[3] + bv;
    }
  }
}

extern "C" void kernel_launch(void* const* d_in, const int* in_sizes, int n_in,
                              void* d_out, int out_size, void* d_ws, size_t ws_size,
                              hipStream_t stream) {
  const float* x = (const float*)d_in[0];
  const int* qw = (const int*)d_in[1];
  const int* qz = (const int*)d_in[2];
  const float* sc = (const float*)d_in[3];
  const float* bias = (const float*)d_in[4];
  float* out = (float*)d_out;

  short* Abf = (short*)d_ws;                          // 67.1 MB bf16 x
  const size_t abytes = (size_t)M_DIM * K_DIM * 2;
  short* Wt = (short*)((char*)d_ws + abytes);         // up to 90.2 MB bf16 W^T chunk
  const size_t remain = (ws_size > abytes) ? ws_size - abytes : 0;
  long nc_max = (long)(remain / ((size_t)K_DIM * 2));
  nc_max = (nc_max / 256) * 256;                      // chunk multiple of 256
  if (nc_max <= 0) return;                            // ws too small -> visible fail
  if (nc_max > N_DIM) nc_max = N_DIM;

  cvt_x_kernel<<<dim3((M_DIM * K_DIM / 8) / 256), 256, 0, stream>>>(x, Abf);

  for (int n0 = 0; n0 < N_DIM; n0 += (int)nc_max) {
    const int nc = (N_DIM - n0 < nc_max) ? (N_DIM - n0) : (int)nc_max;
    dequant_kernel<<<dim3(K_DIM / 64, nc / 256), 256, 0, stream>>>(qw, qz, sc, Wt, n0);
    gemm_kernel<<<dim3(nc / 128, M_DIM / 128), 256, 0, stream>>>(Abf, Wt, bias, out, n0);
  }
}